// Round 10
// baseline (407.648 us; speedup 1.0000x reference)
//
#include <hip/hip_runtime.h>
#include <hip/hip_bf16.h>
#include <cstdint>
#include <cstddef>

#define Bdim 2
#define Sdim 2048
#define Edim 1024
#define Hdim 16
#define Ddim 64
#define KVB 128
#define MROWS (Bdim*Sdim)

typedef __bf16 bf16_t;
typedef __attribute__((ext_vector_type(8))) __bf16 bf16x8;
typedef __attribute__((ext_vector_type(4))) __bf16 bf16x4;
typedef __attribute__((ext_vector_type(4))) float f32x4;

__device__ inline bf16_t f2b(float x) {
    unsigned u = __builtin_bit_cast(unsigned, x);
    unsigned r = u + 0x7fffu + ((u >> 16) & 1u);
    return __builtin_bit_cast(bf16_t, (unsigned short)(r >> 16));
}

// Stage a ROWS x 32 tile (row-major, leading dim ld) into LDS as bf16, rows
// padded to 40 elements. Converts f32 -> bf16 on the fly when T == float.
template<typename T, int ROWS>
__device__ inline void stage_tile(bf16_t* dst, const T* src, int ld, int tid) {
    for (int i = tid; i < ROWS * 4; i += 256) {
        int r = i >> 2;
        int c = (i & 3) * 8;
        const T* s = src + (size_t)r * ld + c;
        bf16x8 v;
        if constexpr (sizeof(T) == 4) {
            const float4* sf = (const float4*)s;
            float4 a = sf[0], b = sf[1];
            v[0] = f2b(a.x); v[1] = f2b(a.y); v[2] = f2b(a.z); v[3] = f2b(a.w);
            v[4] = f2b(b.x); v[5] = f2b(b.y); v[6] = f2b(b.z); v[7] = f2b(b.w);
        } else {
            v = *(const bf16x8*)s;
        }
        *(bf16x8*)(dst + r * 40 + c) = v;
    }
}

// Core: C[128 x BN] += A[128 x K] * B^T, B row-major [BN x K]. 4 waves 2x2.
template<typename TA, typename TB, int FN>
__device__ inline void gemm_core(const TA* A, int lda, const TB* B, int ldb, int K,
                                 f32x4 (&acc)[4][FN]) {
    constexpr int BN = FN * 32;
    __shared__ bf16_t As[128 * 40];
    __shared__ bf16_t Bs[BN * 40];
    const int tid = threadIdx.x;
    const int lane = tid & 63;
    const int w = tid >> 6;
    const int wm = w >> 1, wn = w & 1;
    const int lr = lane & 15, lg = lane >> 4;

    #pragma unroll
    for (int mi = 0; mi < 4; ++mi)
        #pragma unroll
        for (int ni = 0; ni < FN; ++ni)
            acc[mi][ni] = (f32x4){0.f, 0.f, 0.f, 0.f};

    for (int kt = 0; kt < K; kt += 32) {
        __syncthreads();
        stage_tile<TA, 128>(As, A + kt, lda, tid);
        stage_tile<TB, BN>(Bs, B + kt, ldb, tid);
        __syncthreads();
        bf16x8 af[4], bf[FN];
        #pragma unroll
        for (int mi = 0; mi < 4; ++mi)
            af[mi] = *(const bf16x8*)&As[(wm * 64 + mi * 16 + lr) * 40 + lg * 8];
        #pragma unroll
        for (int ni = 0; ni < FN; ++ni)
            bf[ni] = *(const bf16x8*)&Bs[(wn * (FN * 16) + ni * 16 + lr) * 40 + lg * 8];
        #pragma unroll
        for (int mi = 0; mi < 4; ++mi)
            #pragma unroll
            for (int ni = 0; ni < FN; ++ni)
                acc[mi][ni] = __builtin_amdgcn_mfma_f32_16x16x32_bf16(
                    af[mi], bf[ni], acc[mi][ni], 0, 0, 0);
    }
}

// ---- Kernel 0: convert the 4 weight matrices to bf16; Wq scaled by 0.125.
__global__ __launch_bounds__(256) void k_convert(
    const float* __restrict__ Wq, const float* __restrict__ Wk,
    const float* __restrict__ Wv, const float* __restrict__ Wo,
    bf16_t* __restrict__ dst) {
    const int z = blockIdx.y;
    const float* src = (z == 0) ? Wq : (z == 1) ? Wk : (z == 2) ? Wv : Wo;
    const float scale = (z == 0) ? 0.125f : 1.0f;
    bf16_t* d = dst + (size_t)z * Edim * Edim;
    const int i = blockIdx.x * 256 + threadIdx.x;
    const float4* s4 = (const float4*)(src + (size_t)i * 8);
    float4 a = s4[0], b = s4[1];
    bf16x8 v;
    v[0] = f2b(a.x * scale); v[1] = f2b(a.y * scale);
    v[2] = f2b(a.z * scale); v[3] = f2b(a.w * scale);
    v[4] = f2b(b.x * scale); v[5] = f2b(b.y * scale);
    v[6] = f2b(b.z * scale); v[7] = f2b(b.w * scale);
    *(bf16x8*)(d + (size_t)i * 8) = v;
}

// ---- Kernel 1: QKV projections. z = 0/1/2 -> Q/K/V. W pre-converted bf16.
// Q (pre-scaled by 0.125) -> [B,H,S,D]; K,V -> MFMA-fragment-major swizzled:
//   Kswz[bh][s/16][d/8][s%16][d%8]
//   Vswz[bh][s/32][d/16][(s/8)%4][d%16][s%8]
__global__ __launch_bounds__(256) void k_proj(
    const float* __restrict__ xq, const float* __restrict__ xk, const float* __restrict__ xv,
    const bf16_t* __restrict__ Wb,
    const float* __restrict__ bq, const float* __restrict__ bk, const float* __restrict__ bv,
    bf16_t* __restrict__ Qb, bf16_t* __restrict__ Kswz, bf16_t* __restrict__ Vswz) {
    const int z = blockIdx.z;
    const float* X = (z == 0) ? xq : (z == 1) ? xk : xv;
    const bf16_t* W = Wb + (size_t)z * Edim * Edim;
    const float* bias = (z == 0) ? bq : (z == 1) ? bk : bv;
    const float bscale = (z == 0) ? 0.125f : 1.0f;
    const int tm = blockIdx.y, tn = blockIdx.x;
    f32x4 acc[4][4];
    gemm_core<float, bf16_t, 4>(X + (size_t)tm * 128 * Edim, Edim,
                                W + (size_t)tn * 128 * Edim, Edim, Edim, acc);
    const int tid = threadIdx.x, lane = tid & 63, w = tid >> 6;
    const int wm = w >> 1, wn = w & 1, lr = lane & 15, lg = lane >> 4;
    #pragma unroll
    for (int mi = 0; mi < 4; ++mi)
        #pragma unroll
        for (int ni = 0; ni < 4; ++ni)
            #pragma unroll
            for (int j = 0; j < 4; ++j) {
                int gm = tm * 128 + wm * 64 + mi * 16 + lg * 4 + j;
                int gn = tn * 128 + wn * 64 + ni * 16 + lr;
                float v = acc[mi][ni][j] + bias[gn] * bscale;
                int b = gm >> 11, s = gm & (Sdim - 1);
                int h = gn >> 6, d = gn & (Ddim - 1);
                size_t bh = (size_t)(b * Hdim + h);
                if (z == 0) {
                    Qb[(bh * Sdim + s) * Ddim + d] = f2b(v);
                } else if (z == 1) {
                    size_t idx = ((bh * (Sdim / 16) + (s >> 4)) * 8 + (d >> 3)) * 128
                               + (s & 15) * 8 + (d & 7);
                    Kswz[idx] = f2b(v);
                } else {
                    size_t idx = (((bh * (Sdim / 32) + (s >> 5)) * 4 + (d >> 4)) * 4
                               + ((s >> 3) & 3)) * 128 + (d & 15) * 8 + (s & 7);
                    Vswz[idx] = f2b(v);
                }
            }
}

// ---- Kernel 2a: row sums of exp(s). 128-row blocks, wave owns 32 rows.
// Writes il = 1/sum (f32) to Lsum[bh*Sdim + row].
__global__ __launch_bounds__(256) void k_sum(
    const bf16_t* __restrict__ Qb, const bf16_t* __restrict__ Kswz,
    float* __restrict__ Lsum) {
    const int wg = blockIdx.x;                  // 512 blocks
    const int id = ((wg & 7) << 6) | (wg >> 3); // bijective XCD swizzle
    const int bh = id >> 4, qt = id & 15;
    const int tid = threadIdx.x, lane = tid & 63, w = tid >> 6;
    const int lr = lane & 15, lg = lane >> 4;

    const bf16_t* Qp = Qb + ((size_t)bh * Sdim + qt * 128 + w * 32) * Ddim;
    const bf16_t* Kp = Kswz + (size_t)bh * Sdim * Ddim;

    bf16x8 qf[2][2];
    #pragma unroll
    for (int mi = 0; mi < 2; ++mi)
        #pragma unroll
        for (int kk = 0; kk < 2; ++kk)
            qf[mi][kk] = *(const bf16x8*)(Qp + (mi * 16 + lr) * Ddim + kk * 32 + lg * 8);

    float lsum[2][4];
    #pragma unroll
    for (int mi = 0; mi < 2; ++mi)
        #pragma unroll
        for (int j = 0; j < 4; ++j) lsum[mi][j] = 0.f;

    for (int kt = 0; kt < Sdim / KVB; ++kt) {
        bf16x8 kf[8][2];
        #pragma unroll
        for (int ni = 0; ni < 8; ++ni) {
            const bf16_t* kp = Kp + (size_t)(kt * 8 + ni) * 1024 + lane * 8;
            kf[ni][0] = *(const bf16x8*)(kp);
            kf[ni][1] = *(const bf16x8*)(kp + 512);
        }
        #pragma unroll
        for (int ni = 0; ni < 8; ++ni)
            #pragma unroll
            for (int mi = 0; mi < 2; ++mi) {
                f32x4 s = (f32x4){0.f, 0.f, 0.f, 0.f};
                s = __builtin_amdgcn_mfma_f32_16x16x32_bf16(qf[mi][0], kf[ni][0], s, 0, 0, 0);
                s = __builtin_amdgcn_mfma_f32_16x16x32_bf16(qf[mi][1], kf[ni][1], s, 0, 0, 0);
                #pragma unroll
                for (int j = 0; j < 4; ++j) lsum[mi][j] += __expf(s[j]);
            }
    }
    #pragma unroll
    for (int mask = 1; mask <= 8; mask <<= 1)
        #pragma unroll
        for (int mi = 0; mi < 2; ++mi)
            #pragma unroll
            for (int j = 0; j < 4; ++j)
                lsum[mi][j] += __shfl_xor(lsum[mi][j], mask);
    if (lr == 0)
        #pragma unroll
        for (int mi = 0; mi < 2; ++mi)
            #pragma unroll
            for (int j = 0; j < 4; ++j)
                Lsum[(size_t)bh * Sdim + qt * 128 + w * 32 + mi * 16 + lg * 4 + j] =
                    1.0f / lsum[mi][j];
}

// ---- Kernel 2b: recompute S, write normalized P (coalesced via LDS band),
// accumulate O = P.V. 128-row blocks, wave owns 32 rows, zero barriers.
__global__ __launch_bounds__(256) void k_pv(
    const bf16_t* __restrict__ Qb, const bf16_t* __restrict__ Kswz,
    const bf16_t* __restrict__ Vswz, const float* __restrict__ Lsum,
    float* __restrict__ P, bf16_t* __restrict__ AOb) {
    const int wg = blockIdx.x;
    const int id = ((wg & 7) << 6) | (wg >> 3);
    const int bh = id >> 4, qt = id & 15;
    const int b = bh >> 4, h = bh & 15;
    const int tid = threadIdx.x, lane = tid & 63, w = tid >> 6;
    const int lr = lane & 15, lg = lane >> 4;

    __shared__ bf16_t Ps[4][32][132];   // per-wave 32x128 P band

    const bf16_t* Qp = Qb + ((size_t)bh * Sdim + qt * 128 + w * 32) * Ddim;
    const bf16_t* Kp = Kswz + (size_t)bh * Sdim * Ddim;
    const bf16_t* Vp = Vswz + (size_t)bh * Ddim * Sdim;
    float* Pp = P + (size_t)bh * Sdim * Sdim + (size_t)(qt * 128 + w * 32) * Sdim;

    bf16x8 qf[2][2];
    #pragma unroll
    for (int mi = 0; mi < 2; ++mi)
        #pragma unroll
        for (int kk = 0; kk < 2; ++kk)
            qf[mi][kk] = *(const bf16x8*)(Qp + (mi * 16 + lr) * Ddim + kk * 32 + lg * 8);

    float il[2][4];
    #pragma unroll
    for (int mi = 0; mi < 2; ++mi)
        #pragma unroll
        for (int j = 0; j < 4; ++j)
            il[mi][j] = Lsum[(size_t)bh * Sdim + qt * 128 + w * 32 + mi * 16 + lg * 4 + j];

    f32x4 oacc[2][4];
    #pragma unroll
    for (int mi = 0; mi < 2; ++mi)
        #pragma unroll
        for (int nd = 0; nd < 4; ++nd)
            oacc[mi][nd] = (f32x4){0.f, 0.f, 0.f, 0.f};

    for (int kt = 0; kt < Sdim / KVB; ++kt) {
        bf16x8 kf[8][2];
        #pragma unroll
        for (int ni = 0; ni < 8; ++ni) {
            const bf16_t* kp = Kp + (size_t)(kt * 8 + ni) * 1024 + lane * 8;
            kf[ni][0] = *(const bf16x8*)(kp);
            kf[ni][1] = *(const bf16x8*)(kp + 512);
        }
        bf16x8 vf[4][4];
        #pragma unroll
        for (int ks = 0; ks < 4; ++ks)
            #pragma unroll
            for (int nd = 0; nd < 4; ++nd)
                vf[ks][nd] = *(const bf16x8*)(Vp + ((size_t)(kt * 4 + ks) * 4 + nd) * 512 + lane * 8);
        // scores -> exp -> LDS band
        #pragma unroll
        for (int ni = 0; ni < 8; ++ni)
            #pragma unroll
            for (int mi = 0; mi < 2; ++mi) {
                f32x4 s = (f32x4){0.f, 0.f, 0.f, 0.f};
                s = __builtin_amdgcn_mfma_f32_16x16x32_bf16(qf[mi][0], kf[ni][0], s, 0, 0, 0);
                s = __builtin_amdgcn_mfma_f32_16x16x32_bf16(qf[mi][1], kf[ni][1], s, 0, 0, 0);
                #pragma unroll
                for (int j = 0; j < 4; ++j)
                    Ps[w][mi * 16 + lg * 4 + j][ni * 16 + lr] = f2b(__expf(s[j]) * il[mi][j]);
            }
        // coalesced global P write from LDS band
        #pragma unroll
        for (int i = 0; i < 16; ++i) {
            int row = 2 * i + (lane >> 5);
            int col0 = (lane & 31) * 4;
            bf16x4 p4 = *(const bf16x4*)&Ps[w][row][col0];
            f32x4 o;
            o[0] = (float)p4[0]; o[1] = (float)p4[1];
            o[2] = (float)p4[2]; o[3] = (float)p4[3];
            *(f32x4*)&Pp[(size_t)row * Sdim + kt * KVB + col0] = o;
        }
        // PV accumulate
        #pragma unroll
        for (int ks = 0; ks < 4; ++ks) {
            bf16x8 pa[2];
            pa[0] = *(const bf16x8*)&Ps[w][lr][ks * 32 + lg * 8];
            pa[1] = *(const bf16x8*)&Ps[w][16 + lr][ks * 32 + lg * 8];
            #pragma unroll
            for (int nd = 0; nd < 4; ++nd) {
                oacc[0][nd] = __builtin_amdgcn_mfma_f32_16x16x32_bf16(pa[0], vf[ks][nd], oacc[0][nd], 0, 0, 0);
                oacc[1][nd] = __builtin_amdgcn_mfma_f32_16x16x32_bf16(pa[1], vf[ks][nd], oacc[1][nd], 0, 0, 0);
            }
        }
    }

    // epilogue: AO bf16 [B,S,E]
    #pragma unroll
    for (int mi = 0; mi < 2; ++mi)
        #pragma unroll
        for (int nd = 0; nd < 4; ++nd)
            #pragma unroll
            for (int j = 0; j < 4; ++j) {
                int s = qt * 128 + w * 32 + mi * 16 + lg * 4 + j;
                int d = nd * 16 + lr;
                AOb[((size_t)(b * Sdim + s)) * Edim + h * Ddim + d] = f2b(oacc[mi][nd][j]);
            }
}

// ---- Kernel 3: output = AO @ Wo^T + bo -> d_out f32. Wo pre-converted bf16.
__global__ __launch_bounds__(256) void k_oproj(
    const bf16_t* __restrict__ AOb, const bf16_t* __restrict__ Wob,
    const float* __restrict__ bo, float* __restrict__ out) {
    f32x4 acc[4][4];
    gemm_core<bf16_t, bf16_t, 4>(AOb + (size_t)blockIdx.y * 128 * Edim, Edim,
                                 Wob + (size_t)blockIdx.x * 128 * Edim, Edim, Edim, acc);
    const int tid = threadIdx.x, lane = tid & 63, w = tid >> 6;
    const int wm = w >> 1, wn = w & 1, lr = lane & 15, lg = lane >> 4;
    #pragma unroll
    for (int mi = 0; mi < 4; ++mi)
        #pragma unroll
        for (int ni = 0; ni < 4; ++ni)
            #pragma unroll
            for (int j = 0; j < 4; ++j) {
                int gm = blockIdx.y * 128 + wm * 64 + mi * 16 + lg * 4 + j;
                int gn = blockIdx.x * 128 + wn * 64 + ni * 16 + lr;
                out[(size_t)gm * Edim + gn] = acc[mi][ni][j] + bo[gn];
            }
}

extern "C" void kernel_launch(void* const* d_in, const int* in_sizes, int n_in,
                              void* d_out, int out_size, void* d_ws, size_t ws_size,
                              hipStream_t stream) {
    const float* query = (const float*)d_in[0];
    const float* key_  = (const float*)d_in[1];
    const float* value = (const float*)d_in[2];
    const float* Wq = (const float*)d_in[3];
    const float* bq = (const float*)d_in[4];
    const float* Wk = (const float*)d_in[5];
    const float* bk = (const float*)d_in[6];
    const float* Wv = (const float*)d_in[7];
    const float* bv = (const float*)d_in[8];
    const float* Wo = (const float*)d_in[9];
    const float* bo = (const float*)d_in[10];

    float* out = (float*)d_out;                      // [4096][1024]
    float* P = out + (size_t)MROWS * Edim;           // [32][2048][2048] attn weights

    const size_t WSZ = (size_t)Edim * Edim;                 // 1M elems per W
    const size_t HSD = (size_t)Bdim * Hdim * Sdim * Ddim;   // 4M elems
    bf16_t* Wb   = (bf16_t*)d_ws;       // 4 x [E,E]  (Wq*0.125, Wk, Wv, Wo)
    bf16_t* Qb   = Wb + 4 * WSZ;        // [B,H,S,D]  (pre-scaled)
    bf16_t* Kswz = Qb + HSD;            // fragment-major K
    bf16_t* Vswz = Kswz + HSD;          // fragment-major V
    bf16_t* AOb  = Vswz + HSD;          // [B,S,E]
    // Lsum reuses the Wq*0.125 region (dead after k_proj): 128KB of 2MB.
    float* Lsum  = (float*)Wb;

    k_convert<<<dim3(512, 4), 256, 0, stream>>>(Wq, Wk, Wv, Wo, Wb);
    k_proj<<<dim3(8, 32, 3), 256, 0, stream>>>(query, key_, value, Wb,
                                               bq, bk, bv, Qb, Kswz, Vswz);
    k_sum<<<dim3(512), 256, 0, stream>>>(Qb, Kswz, Lsum);
    k_pv<<<dim3(512), 256, 0, stream>>>(Qb, Kswz, Vswz, Lsum, P, AOb);
    k_oproj<<<dim3(8, 32, 1), 256, 0, stream>>>(AOb, Wb + 3 * WSZ, bo, out);
}